// Round 13
// baseline (61.483 us; speedup 1.0000x reference)
//
#include <hip/hip_runtime.h>

typedef __bf16 bf16x8 __attribute__((ext_vector_type(8)));
typedef __bf16 bf16x4 __attribute__((ext_vector_type(4)));
typedef float f32x16 __attribute__((ext_vector_type(16)));
typedef float f32x4 __attribute__((ext_vector_type(4)));

constexpr int S = 128, R = 256, CM = 256, C = 32, CZ = 128;

#define MFMA __builtin_amdgcn_mfma_f32_32x32x16_bf16

typedef __attribute__((address_space(3))) void lds_void;
typedef const __attribute__((address_space(1))) void gbl_void;

__device__ __forceinline__ bf16x4 cvt4(float a, float b, float c, float d) {
    bf16x4 r;
    r[0] = (__bf16)a; r[1] = (__bf16)b; r[2] = (__bf16)c; r[3] = (__bf16)d;
    return r;
}

// K0: merged prep. blocks 0..511: WTf[((k>>3)*128+cz)*8+(k&7)] = bf16(W[(c*32+e)*128+cz]);
// blocks 512..575: WLRT[c][m] from left/right.
__global__ __launch_bounds__(256) void k_prep(const float* __restrict__ W,
                                              const float* __restrict__ Lp,
                                              const float* __restrict__ Rp,
                                              __bf16* __restrict__ WTf,
                                              __bf16* __restrict__ WLRT) {
    int b = blockIdx.x;
    if (b < 512) {
        int g = b * 256 + threadIdx.x;
        int cz = g & 127;
        int k = g >> 7;
        int e = k >> 5, c = k & 31;
        float v = W[(size_t)(c * 32 + e) * 128 + cz];
        WTf[((size_t)(k >> 3) * 128 + cz) * 8 + (k & 7)] = (__bf16)v;
    } else {
        int c = b - 512;
        int m = threadIdx.x;
        const float* src = (c < 32) ? Lp : Rp;
        WLRT[(size_t)c * 256 + m] = (__bf16)src[(size_t)m * 32 + (c & 31)];
    }
}

// K1: block (r, s-quarter=32 rows), 256 thr / 4 waves = (ksh x sd).
// K(m)-split halves + 2-way LDS reduction. Writes aTf/bTf[r][ks][khf][c][8s].
__global__ __launch_bounds__(256) void k_proj(const float* __restrict__ msa,
                                              const __bf16* __restrict__ WLRT,
                                              __bf16* __restrict__ aTf,
                                              __bf16* __restrict__ bTf) {
    __shared__ __align__(16) __bf16 As[32 * 256];       // 16 KB
    __shared__ __align__(16) char Pp[2 * 4096];         // 8 KB partials
    const int r = blockIdx.x;
    const int sq = blockIdx.y;                          // 0..3
    const int t = threadIdx.x;

#pragma unroll
    for (int it = 0; it < 8; ++it) {
        int idx = it * 256 + t;
        int row = idx >> 6;            // 0..31
        int cg = idx & 63;
        float4 v = *(const float4*)&msa[((size_t)(sq * 32 + row) * R + r) * CM + cg * 4];
        bf16x4 h = cvt4(v.x, v.y, v.z, v.w);
        int P = (cg >> 1) ^ (row & 15);
        *(bf16x4*)((char*)As + row * 512 + P * 16 + (cg & 1) * 8) = h;
    }
    __syncthreads();

    const int w = t >> 6;
    const int l = t & 63;
    const int l31 = t & 31;
    const int kh = (t >> 5) & 1;
    const int sd = w & 1;              // 0 = left, 1 = right
    const int ksh = w >> 1;            // m-half

    f32x16 acc;
#pragma unroll
    for (int q = 0; q < 16; ++q) acc[q] = 0.f;

    const bf16x8* wb = (const bf16x8*)&WLRT[(size_t)(sd * 32 + l31) * 256 + 8 * kh];
    const char* arow = (const char*)As + l31 * 512;

    __builtin_amdgcn_s_setprio(1);
#pragma unroll
    for (int j = 0; j < 8; ++j) {
        int ks = ksh * 8 + j;
        int P = (2 * ks + kh) ^ (l31 & 15);
        bf16x8 af = *(const bf16x8*)(arow + P * 16);
        acc = MFMA(af, wb[2 * ks], acc, 0, 0, 0);
    }
    __builtin_amdgcn_s_setprio(0);

    char* pbase = Pp + (size_t)sd * 4096;
    if (ksh == 1) {
#pragma unroll
        for (int pc = 0; pc < 4; ++pc) {
            f32x4 v;
            v[0] = acc[4 * pc + 0]; v[1] = acc[4 * pc + 1];
            v[2] = acc[4 * pc + 2]; v[3] = acc[4 * pc + 3];
            *(f32x4*)(pbase + ((pc * 64) + l) * 16) = v;
        }
    }
    __syncthreads();
    if (ksh == 0) {
#pragma unroll
        for (int pc = 0; pc < 4; ++pc) {
            f32x4 v = *(const f32x4*)(pbase + ((pc * 64) + l) * 16);
            acc[4 * pc + 0] += v[0]; acc[4 * pc + 1] += v[1];
            acc[4 * pc + 2] += v[2]; acc[4 * pc + 3] += v[3];
        }
        __bf16* dst = sd ? bTf : aTf;
#pragma unroll
        for (int q = 0; q < 4; ++q) {
            size_t base = (size_t)r * 4096 + (size_t)(2 * sq + (q >> 1)) * 512 +
                          (size_t)(q & 1) * 256 + (size_t)l31 * 8 + 4 * kh;
            *(bf16x4*)&dst[base] = cvt4(acc[4 * q + 0], acc[4 * q + 1],
                                        acc[4 * q + 2], acc[4 * q + 3]);
        }
    }
}

// K2: 64 pairs (8r x 8t), 512 thr / 8 waves, 128 KB LDS.
// Stage: a+b tiles (128 KB, zero-dup) -> LDS via global_load_lds DMA.
// Phase A: wave (rg,tg) 2r x 4t, operands from LDS (depth-2 ping-pong).
// barrier -> G (swizzled) overwrites staging region.
// Phase B: r12 asm W pipeline (32 loads up front, counted vmcnt), K-split,
// 4-way reduction via dead-G LDS partials.
__global__ __launch_bounds__(512, 2) void k_main(const __bf16* __restrict__ aTf,
                                                 const __bf16* __restrict__ bTf,
                                                 const __bf16* __restrict__ WTf,
                                                 float* __restrict__ out) {
    __shared__ __align__(16) __bf16 Gs[64 * 1024];   // 128 KB (b[0,64K) a[64K,128K) -> G -> partials)

    const int t = threadIdx.x;
    const int w = t >> 6;              // 0..7
    const int l = t & 63;
    const int lane = l & 31;
    const int kh = l >> 5;
    const int r0 = blockIdx.x * 8;
    const int t0 = blockIdx.y * 8;

    // ---------------- DMA stage: b -> [0,64K), a -> [64K,128K) ----------------
    {
        const char* bsrc = (const char*)bTf + (size_t)t0 * 8192;
        const char* asrc = (const char*)aTf + (size_t)r0 * 8192;
        char* ldsb = (char*)Gs;
        const unsigned wu = (unsigned)w * 1024;       // wave-uniform part of t*16
#pragma unroll
        for (int i = 0; i < 8; ++i) {
            __builtin_amdgcn_global_load_lds(
                (gbl_void*)(bsrc + (size_t)i * 8192 + (size_t)t * 16),
                (lds_void*)(ldsb + i * 8192 + wu), 16, 0, 0);
        }
#pragma unroll
        for (int i = 0; i < 8; ++i) {
            __builtin_amdgcn_global_load_lds(
                (gbl_void*)(asrc + (size_t)i * 8192 + (size_t)t * 16),
                (lds_void*)(ldsb + 65536 + i * 8192 + wu), 16, 0, 0);
        }
    }
    asm volatile("s_waitcnt vmcnt(0)");
    __builtin_amdgcn_sched_barrier(0);
    __syncthreads();

    // ---------------- Phase A (operands from LDS) ----------------
    const int rg = w & 3;
    const int tg = w >> 2;

    f32x16 acc[2][4];
#pragma unroll
    for (int i = 0; i < 2; ++i)
#pragma unroll
        for (int j = 0; j < 4; ++j)
#pragma unroll
            for (int q = 0; q < 16; ++q) acc[i][j][q] = 0.f;

    const char* aL0 = (const char*)Gs + 65536 + (2 * rg + 0) * 8192 + kh * 512 + lane * 16;
    const char* aL1 = (const char*)Gs + 65536 + (2 * rg + 1) * 8192 + kh * 512 + lane * 16;
    const char* bL0 = (const char*)Gs + (4 * tg + 0) * 8192 + kh * 512 + lane * 16;
    const char* bL1 = (const char*)Gs + (4 * tg + 1) * 8192 + kh * 512 + lane * 16;
    const char* bL2 = (const char*)Gs + (4 * tg + 2) * 8192 + kh * 512 + lane * 16;
    const char* bL3 = (const char*)Gs + (4 * tg + 3) * 8192 + kh * 512 + lane * 16;

    bf16x8 A0[2], B0[4], A1[2], B1[4];
#define LDA(Aa, Bb, ks) do { \
    Aa[0] = *(const bf16x8*)(aL0 + (ks) * 1024); \
    Aa[1] = *(const bf16x8*)(aL1 + (ks) * 1024); \
    Bb[0] = *(const bf16x8*)(bL0 + (ks) * 1024); \
    Bb[1] = *(const bf16x8*)(bL1 + (ks) * 1024); \
    Bb[2] = *(const bf16x8*)(bL2 + (ks) * 1024); \
    Bb[3] = *(const bf16x8*)(bL3 + (ks) * 1024); } while (0)
#define PH_A(Aa, Bb) do { \
    __builtin_amdgcn_s_setprio(1); \
    acc[0][0] = MFMA(Aa[0], Bb[0], acc[0][0], 0, 0, 0); \
    acc[0][1] = MFMA(Aa[0], Bb[1], acc[0][1], 0, 0, 0); \
    acc[0][2] = MFMA(Aa[0], Bb[2], acc[0][2], 0, 0, 0); \
    acc[0][3] = MFMA(Aa[0], Bb[3], acc[0][3], 0, 0, 0); \
    acc[1][0] = MFMA(Aa[1], Bb[0], acc[1][0], 0, 0, 0); \
    acc[1][1] = MFMA(Aa[1], Bb[1], acc[1][1], 0, 0, 0); \
    acc[1][2] = MFMA(Aa[1], Bb[2], acc[1][2], 0, 0, 0); \
    acc[1][3] = MFMA(Aa[1], Bb[3], acc[1][3], 0, 0, 0); \
    __builtin_amdgcn_s_setprio(0); } while (0)

    LDA(A0, B0, 0);
#pragma unroll
    for (int ks = 0; ks < 8; ks += 2) {
        LDA(A1, B1, ks + 1);
        PH_A(A0, B0);
        LDA(A0, B0, (ks + 2) & 7);
        PH_A(A1, B1);
    }
    __syncthreads();   // all staging reads complete; region becomes G

    // ---------------- G -> LDS (swizzled), overwriting staging ----------------
#pragma unroll
    for (int i = 0; i < 2; ++i) {
#pragma unroll
        for (int j = 0; j < 4; ++j) {
            int p = (2 * rg + i) * 8 + 4 * tg + j;
            unsigned prow = (unsigned)p * 2048;
#pragma unroll
            for (int q = 0; q < 4; ++q) {
                int Lc = lane * 4 + q;
                int P = Lc ^ (p & 15) ^ (lane & 7);
                *(bf16x4*)((char*)Gs + prow + (unsigned)P * 16 + kh * 8) =
                    cvt4(acc[i][j][4 * q + 0], acc[i][j][4 * q + 1],
                         acc[i][j][4 * q + 2], acc[i][j][4 * q + 3]);
            }
        }
    }
    __syncthreads();

    // ---------------- Phase B (asm-pipelined W stream) ----------------
    const int kq = w >> 1;             // K-quarter 0..3
    const int ng = w & 1;              // cz pair-group
    const int czl0 = ng * 64 + lane;
    const int czl1 = czl0 + 32;
    const char* wb0c = (const char*)WTf + ((size_t)kh * 128 + czl0) * 16;
    const char* wb1c = (const char*)WTf + ((size_t)kh * 128 + czl1) * 16;
    const unsigned prow0 = (unsigned)lane * 2048;
    const unsigned prow1 = (unsigned)(lane + 32) * 2048;
    const int p15 = lane & 15;

    f32x16 o00, o01, o10, o11;
#pragma unroll
    for (int q = 0; q < 16; ++q) { o00[q] = 0.f; o01[q] = 0.f; o10[q] = 0.f; o11[q] = 0.f; }

    // Issue the wave's ENTIRE W stream: 32 loads held in flight by raw asm.
    bf16x8 Wp[16][2];
#pragma unroll
    for (int s = 0; s < 16; ++s) {
        const char* a0 = wb0c + (size_t)(kq * 16 + s) * 4096;
        const char* a1 = wb1c + (size_t)(kq * 16 + s) * 4096;
        asm volatile("global_load_dwordx4 %0, %1, off" : "=v"(Wp[s][0]) : "v"(a0));
        asm volatile("global_load_dwordx4 %0, %1, off" : "=v"(Wp[s][1]) : "v"(a1));
    }

    bf16x8 Gp[4][2];
#define LDG(sl, kk) do { \
    int Lr = (kk) * 2 + kh; \
    int P = Lr ^ p15 ^ ((Lr >> 2) & 7); \
    Gp[sl][0] = *(const bf16x8*)((const char*)Gs + prow0 + (unsigned)P * 16); \
    Gp[sl][1] = *(const bf16x8*)((const char*)Gs + prow1 + (unsigned)P * 16); } while (0)

    LDG(0, kq * 16 + 0);
    LDG(1, kq * 16 + 1);
    LDG(2, kq * 16 + 2);
    LDG(3, kq * 16 + 3);

#define STEPB(j, cnt) do { \
    asm volatile("s_waitcnt vmcnt(" #cnt ")"); \
    __builtin_amdgcn_sched_barrier(0); \
    __builtin_amdgcn_s_setprio(1); \
    o00 = MFMA(Gp[(j) & 3][0], Wp[j][0], o00, 0, 0, 0); \
    o01 = MFMA(Gp[(j) & 3][0], Wp[j][1], o01, 0, 0, 0); \
    o10 = MFMA(Gp[(j) & 3][1], Wp[j][0], o10, 0, 0, 0); \
    o11 = MFMA(Gp[(j) & 3][1], Wp[j][1], o11, 0, 0, 0); \
    __builtin_amdgcn_s_setprio(0); \
    if ((j) + 4 < 16) LDG((j) & 3, kq * 16 + (j) + 4); \
} while (0)

    STEPB(0, 30);  STEPB(1, 28);  STEPB(2, 26);  STEPB(3, 24);
    STEPB(4, 22);  STEPB(5, 20);  STEPB(6, 18);  STEPB(7, 16);
    STEPB(8, 14);  STEPB(9, 12);  STEPB(10, 10); STEPB(11, 8);
    STEPB(12, 6);  STEPB(13, 4);  STEPB(14, 2);  STEPB(15, 0);

    __syncthreads();   // all G reads done; region reusable for partials

    // partials: region w*16KB, layout [s2][piece][l] x 16B, s2 = (M,slice)
    {
        char* pr = (char*)Gs + (size_t)w * 16384;
        const f32x16* os[4] = {&o00, &o01, &o10, &o11};
#pragma unroll
        for (int s2 = 0; s2 < 4; ++s2) {
#pragma unroll
            for (int pc = 0; pc < 4; ++pc) {
                f32x4 v;
                v[0] = (*os[s2])[4 * pc + 0]; v[1] = (*os[s2])[4 * pc + 1];
                v[2] = (*os[s2])[4 * pc + 2]; v[3] = (*os[s2])[4 * pc + 3];
                *(f32x4*)(pr + ((s2 * 4 + pc) * 64 + l) * 16) = v;
            }
        }
    }
    __syncthreads();

    // reduce over K-quarters: wave (ngx=w>>2, mix=(w>>1)&1, nix=w&1)
    {
        const int ngx = w >> 2;
        const int mix = (w >> 1) & 1;
        const int nix = w & 1;
        const int s2 = mix * 2 + nix;
        f32x16 sm;
#pragma unroll
        for (int q = 0; q < 16; ++q) sm[q] = 0.f;
#pragma unroll
        for (int kq2 = 0; kq2 < 4; ++kq2) {
            const char* pr = (const char*)Gs + (size_t)(kq2 * 2 + ngx) * 16384;
#pragma unroll
            for (int pc = 0; pc < 4; ++pc) {
                f32x4 v = *(const f32x4*)(pr + ((s2 * 4 + pc) * 64 + l) * 16);
                sm[4 * pc + 0] += v[0]; sm[4 * pc + 1] += v[1];
                sm[4 * pc + 2] += v[2]; sm[4 * pc + 3] += v[3];
            }
        }
        const int czl = ngx * 64 + nix * 32 + (l & 31);
        const int khx = l >> 5;
#pragma unroll
        for (int reg = 0; reg < 16; ++reg) {
            int pl = mix * 32 + (reg & 3) + 8 * (reg >> 2) + 4 * khx;
            int prr = pl >> 3, ptt = pl & 7;
            out[((size_t)(r0 + prr) * 256 + (t0 + ptt)) * 128 + czl] = sm[reg];
        }
    }
}

extern "C" void kernel_launch(void* const* d_in, const int* in_sizes, int n_in,
                              void* d_out, int out_size, void* d_ws, size_t ws_size,
                              hipStream_t stream) {
    const float* msa = (const float*)d_in[0];
    const float* left = (const float*)d_in[1];
    const float* right = (const float*)d_in[2];
    const float* W = (const float*)d_in[3];

    __bf16* aTf = (__bf16*)d_ws;                        // 2 MB
    __bf16* bTf = aTf + (size_t)R * 4096;               // 2 MB
    __bf16* WTf = bTf + (size_t)R * 4096;               // 256 KB
    __bf16* WLRT = WTf + (size_t)128 * 1024;            // 32 KB
    float* outp = (float*)d_out;

    k_prep<<<576, 256, 0, stream>>>(W, left, right, WTf, WLRT);
    k_proj<<<dim3(256, 4), 256, 0, stream>>>(msa, WLRT, aTf, bTf);
    k_main<<<dim3(32, 32), 512, 0, stream>>>(aTf, bTf, WTf, outp);
}

// Round 14
// 58.921 us; speedup vs baseline: 1.0435x; 1.0435x over previous
//
#include <hip/hip_runtime.h>

typedef __bf16 bf16x8 __attribute__((ext_vector_type(8)));
typedef __bf16 bf16x4 __attribute__((ext_vector_type(4)));
typedef float f32x16 __attribute__((ext_vector_type(16)));
typedef float f32x4 __attribute__((ext_vector_type(4)));

constexpr int S = 128, R = 256, CM = 256, C = 32, CZ = 128;

#define MFMA __builtin_amdgcn_mfma_f32_32x32x16_bf16

__device__ __forceinline__ bf16x4 cvt4(float a, float b, float c, float d) {
    bf16x4 r;
    r[0] = (__bf16)a; r[1] = (__bf16)b; r[2] = (__bf16)c; r[3] = (__bf16)d;
    return r;
}

// K0: merged prep. blocks 0..511: WTf[((k>>3)*128+cz)*8+(k&7)] = bf16(W[(c*32+e)*128+cz]);
// blocks 512..575: WLRT[c][m] from left/right.
__global__ __launch_bounds__(256) void k_prep(const float* __restrict__ W,
                                              const float* __restrict__ Lp,
                                              const float* __restrict__ Rp,
                                              __bf16* __restrict__ WTf,
                                              __bf16* __restrict__ WLRT) {
    int b = blockIdx.x;
    if (b < 512) {
        int g = b * 256 + threadIdx.x;
        int cz = g & 127;
        int k = g >> 7;
        int e = k >> 5, c = k & 31;
        float v = W[(size_t)(c * 32 + e) * 128 + cz];
        WTf[((size_t)(k >> 3) * 128 + cz) * 8 + (k & 7)] = (__bf16)v;
    } else {
        int c = b - 512;
        int m = threadIdx.x;
        const float* src = (c < 32) ? Lp : Rp;
        WLRT[(size_t)c * 256 + m] = (__bf16)src[(size_t)m * 32 + (c & 31)];
    }
}

// K1: block (r, s-quarter=32 rows), 256 thr / 4 waves = (ksh x sd).
// K(m)-split halves + 2-way LDS reduction. Writes aTf/bTf[r][ks][khf][c][8s].
__global__ __launch_bounds__(256) void k_proj(const float* __restrict__ msa,
                                              const __bf16* __restrict__ WLRT,
                                              __bf16* __restrict__ aTf,
                                              __bf16* __restrict__ bTf) {
    __shared__ __align__(16) __bf16 As[32 * 256];       // 16 KB
    __shared__ __align__(16) char Pp[2 * 4096];         // 8 KB partials
    const int r = blockIdx.x;
    const int sq = blockIdx.y;                          // 0..3
    const int t = threadIdx.x;

#pragma unroll
    for (int it = 0; it < 8; ++it) {
        int idx = it * 256 + t;
        int row = idx >> 6;            // 0..31
        int cg = idx & 63;
        float4 v = *(const float4*)&msa[((size_t)(sq * 32 + row) * R + r) * CM + cg * 4];
        bf16x4 h = cvt4(v.x, v.y, v.z, v.w);
        int P = (cg >> 1) ^ (row & 15);
        *(bf16x4*)((char*)As + row * 512 + P * 16 + (cg & 1) * 8) = h;
    }
    __syncthreads();

    const int w = t >> 6;
    const int l = t & 63;
    const int l31 = t & 31;
    const int kh = (t >> 5) & 1;
    const int sd = w & 1;              // 0 = left, 1 = right
    const int ksh = w >> 1;            // m-half

    f32x16 acc;
#pragma unroll
    for (int q = 0; q < 16; ++q) acc[q] = 0.f;

    const bf16x8* wb = (const bf16x8*)&WLRT[(size_t)(sd * 32 + l31) * 256 + 8 * kh];
    const char* arow = (const char*)As + l31 * 512;

    __builtin_amdgcn_s_setprio(1);
#pragma unroll
    for (int j = 0; j < 8; ++j) {
        int ks = ksh * 8 + j;
        int P = (2 * ks + kh) ^ (l31 & 15);
        bf16x8 af = *(const bf16x8*)(arow + P * 16);
        acc = MFMA(af, wb[2 * ks], acc, 0, 0, 0);
    }
    __builtin_amdgcn_s_setprio(0);

    char* pbase = Pp + (size_t)sd * 4096;
    if (ksh == 1) {
#pragma unroll
        for (int pc = 0; pc < 4; ++pc) {
            f32x4 v;
            v[0] = acc[4 * pc + 0]; v[1] = acc[4 * pc + 1];
            v[2] = acc[4 * pc + 2]; v[3] = acc[4 * pc + 3];
            *(f32x4*)(pbase + ((pc * 64) + l) * 16) = v;
        }
    }
    __syncthreads();
    if (ksh == 0) {
#pragma unroll
        for (int pc = 0; pc < 4; ++pc) {
            f32x4 v = *(const f32x4*)(pbase + ((pc * 64) + l) * 16);
            acc[4 * pc + 0] += v[0]; acc[4 * pc + 1] += v[1];
            acc[4 * pc + 2] += v[2]; acc[4 * pc + 3] += v[3];
        }
        __bf16* dst = sd ? bTf : aTf;
#pragma unroll
        for (int q = 0; q < 4; ++q) {
            size_t base = (size_t)r * 4096 + (size_t)(2 * sq + (q >> 1)) * 512 +
                          (size_t)(q & 1) * 256 + (size_t)l31 * 8 + 4 * kh;
            *(bf16x4*)&dst[base] = cvt4(acc[4 * q + 0], acc[4 * q + 1],
                                        acc[4 * q + 2], acc[4 * q + 3]);
        }
    }
}

// K2: 64 pairs (8r x 8t), 512 thr / 8 waves, G in 128 KB LDS.
// Phase A: depth-3 rotating prefetch (r10 form).
// G-write: cvt+ds_write interleaved with issuing the wave's 32 W asm loads.
// Phase boundary: lgkmcnt-only s_barrier -- W loads STAY IN FLIGHT across it.
// Phase B: counted-vmcnt STEPB stream (r12 form). 4-way K reduction via LDS.
__global__ __launch_bounds__(512, 2) void k_main(const __bf16* __restrict__ aTf,
                                                 const __bf16* __restrict__ bTf,
                                                 const __bf16* __restrict__ WTf,
                                                 float* __restrict__ out) {
    __shared__ __align__(16) __bf16 Gs[64 * 1024];   // 128 KB

    const int t = threadIdx.x;
    const int w = t >> 6;              // 0..7
    const int l = t & 63;
    const int lane = l & 31;
    const int kh = l >> 5;
    const int r0 = blockIdx.x * 8;
    const int t0 = blockIdx.y * 8;

    // ---------------- Phase A ----------------
    const int rg = w & 3;
    const int tg = w >> 2;

    f32x16 acc[2][4];
#pragma unroll
    for (int i = 0; i < 2; ++i)
#pragma unroll
        for (int j = 0; j < 4; ++j)
#pragma unroll
            for (int q = 0; q < 16; ++q) acc[i][j][q] = 0.f;

    const bf16x8* ap0 = (const bf16x8*)aTf + ((size_t)(r0 + 2 * rg + 0) * 512 + kh * 32 + lane);
    const bf16x8* ap1 = (const bf16x8*)aTf + ((size_t)(r0 + 2 * rg + 1) * 512 + kh * 32 + lane);
    const bf16x8* bp0 = (const bf16x8*)bTf + ((size_t)(t0 + 4 * tg + 0) * 512 + kh * 32 + lane);
    const bf16x8* bp1 = (const bf16x8*)bTf + ((size_t)(t0 + 4 * tg + 1) * 512 + kh * 32 + lane);
    const bf16x8* bp2 = (const bf16x8*)bTf + ((size_t)(t0 + 4 * tg + 2) * 512 + kh * 32 + lane);
    const bf16x8* bp3 = (const bf16x8*)bTf + ((size_t)(t0 + 4 * tg + 3) * 512 + kh * 32 + lane);

    bf16x8 Ap[3][2], Bp[3][4];
#pragma unroll
    for (int s = 0; s < 3; ++s) {
        Ap[s][0] = ap0[s * 64]; Ap[s][1] = ap1[s * 64];
        Bp[s][0] = bp0[s * 64]; Bp[s][1] = bp1[s * 64];
        Bp[s][2] = bp2[s * 64]; Bp[s][3] = bp3[s * 64];
    }
#pragma unroll
    for (int ks = 0; ks < 8; ++ks) {
        const int s = ks % 3;
        __builtin_amdgcn_s_setprio(1);
        acc[0][0] = MFMA(Ap[s][0], Bp[s][0], acc[0][0], 0, 0, 0);
        acc[0][1] = MFMA(Ap[s][0], Bp[s][1], acc[0][1], 0, 0, 0);
        acc[0][2] = MFMA(Ap[s][0], Bp[s][2], acc[0][2], 0, 0, 0);
        acc[0][3] = MFMA(Ap[s][0], Bp[s][3], acc[0][3], 0, 0, 0);
        acc[1][0] = MFMA(Ap[s][1], Bp[s][0], acc[1][0], 0, 0, 0);
        acc[1][1] = MFMA(Ap[s][1], Bp[s][1], acc[1][1], 0, 0, 0);
        acc[1][2] = MFMA(Ap[s][1], Bp[s][2], acc[1][2], 0, 0, 0);
        acc[1][3] = MFMA(Ap[s][1], Bp[s][3], acc[1][3], 0, 0, 0);
        __builtin_amdgcn_s_setprio(0);
        if (ks + 3 < 8) {
            const int kn = ks + 3;
            Ap[s][0] = ap0[kn * 64]; Ap[s][1] = ap1[kn * 64];
            Bp[s][0] = bp0[kn * 64]; Bp[s][1] = bp1[kn * 64];
            Bp[s][2] = bp2[kn * 64]; Bp[s][3] = bp3[kn * 64];
        }
    }

    // -------- G-write interleaved with W-issue (acc dies, Wp grows) --------
    const int kq = w >> 1;             // K-quarter 0..3
    const int ng = w & 1;              // cz pair-group
    const int czl0 = ng * 64 + lane;
    const int czl1 = czl0 + 32;
    const char* wb0c = (const char*)WTf + ((size_t)kh * 128 + czl0) * 16;
    const char* wb1c = (const char*)WTf + ((size_t)kh * 128 + czl1) * 16;

    bf16x8 Wp[16][2];
#pragma unroll
    for (int i = 0; i < 2; ++i) {
#pragma unroll
        for (int j = 0; j < 4; ++j) {
            int p = (2 * rg + i) * 8 + 4 * tg + j;
            unsigned prow = (unsigned)p * 2048;
#pragma unroll
            for (int q = 0; q < 4; ++q) {
                int Lc = lane * 4 + q;
                int P = Lc ^ (p & 15) ^ (lane & 7);
                *(bf16x4*)((char*)Gs + prow + (unsigned)P * 16 + kh * 8) =
                    cvt4(acc[i][j][4 * q + 0], acc[i][j][4 * q + 1],
                         acc[i][j][4 * q + 2], acc[i][j][4 * q + 3]);
            }
            // issue 4 W loads for frag-slots 2u, 2u+1 (u = i*4+j)
            {
                const int u = i * 4 + j;
                const char* a0 = wb0c + (size_t)(kq * 16 + 2 * u) * 4096;
                const char* a1 = wb1c + (size_t)(kq * 16 + 2 * u) * 4096;
                const char* a2 = wb0c + (size_t)(kq * 16 + 2 * u + 1) * 4096;
                const char* a3 = wb1c + (size_t)(kq * 16 + 2 * u + 1) * 4096;
                asm volatile("global_load_dwordx4 %0, %1, off" : "=v"(Wp[2 * u][0]) : "v"(a0));
                asm volatile("global_load_dwordx4 %0, %1, off" : "=v"(Wp[2 * u][1]) : "v"(a1));
                asm volatile("global_load_dwordx4 %0, %1, off" : "=v"(Wp[2 * u + 1][0]) : "v"(a2));
                asm volatile("global_load_dwordx4 %0, %1, off" : "=v"(Wp[2 * u + 1][1]) : "v"(a3));
            }
        }
    }

    // Phase boundary: drain LDS ops only; W loads remain in flight.
    asm volatile("s_waitcnt lgkmcnt(0)" ::: "memory");
    __builtin_amdgcn_s_barrier();
    __builtin_amdgcn_sched_barrier(0);

    // ---------------- Phase B (streaming counted-vmcnt) ----------------
    const unsigned prow0 = (unsigned)lane * 2048;
    const unsigned prow1 = (unsigned)(lane + 32) * 2048;
    const int p15 = lane & 15;

    f32x16 o00, o01, o10, o11;
#pragma unroll
    for (int q = 0; q < 16; ++q) { o00[q] = 0.f; o01[q] = 0.f; o10[q] = 0.f; o11[q] = 0.f; }

    bf16x8 Gp[4][2];
#define LDG(sl, kk) do { \
    int Lr = (kk) * 2 + kh; \
    int P = Lr ^ p15 ^ ((Lr >> 2) & 7); \
    Gp[sl][0] = *(const bf16x8*)((const char*)Gs + prow0 + (unsigned)P * 16); \
    Gp[sl][1] = *(const bf16x8*)((const char*)Gs + prow1 + (unsigned)P * 16); } while (0)

    LDG(0, kq * 16 + 0);
    LDG(1, kq * 16 + 1);
    LDG(2, kq * 16 + 2);
    LDG(3, kq * 16 + 3);

#define STEPB(j, cnt) do { \
    asm volatile("s_waitcnt vmcnt(" #cnt ")"); \
    __builtin_amdgcn_sched_barrier(0); \
    __builtin_amdgcn_s_setprio(1); \
    o00 = MFMA(Gp[(j) & 3][0], Wp[j][0], o00, 0, 0, 0); \
    o01 = MFMA(Gp[(j) & 3][0], Wp[j][1], o01, 0, 0, 0); \
    o10 = MFMA(Gp[(j) & 3][1], Wp[j][0], o10, 0, 0, 0); \
    o11 = MFMA(Gp[(j) & 3][1], Wp[j][1], o11, 0, 0, 0); \
    __builtin_amdgcn_s_setprio(0); \
    if ((j) + 4 < 16) LDG((j) & 3, kq * 16 + (j) + 4); \
} while (0)

    STEPB(0, 30);  STEPB(1, 28);  STEPB(2, 26);  STEPB(3, 24);
    STEPB(4, 22);  STEPB(5, 20);  STEPB(6, 18);  STEPB(7, 16);
    STEPB(8, 14);  STEPB(9, 12);  STEPB(10, 10); STEPB(11, 8);
    STEPB(12, 6);  STEPB(13, 4);  STEPB(14, 2);  STEPB(15, 0);

    __syncthreads();   // all G reads done; region reusable for partials

    // partials: region w*16KB, layout [s2][piece][l] x 16B, s2 = (M,slice)
    {
        char* pr = (char*)Gs + (size_t)w * 16384;
        const f32x16* os[4] = {&o00, &o01, &o10, &o11};
#pragma unroll
        for (int s2 = 0; s2 < 4; ++s2) {
#pragma unroll
            for (int pc = 0; pc < 4; ++pc) {
                f32x4 v;
                v[0] = (*os[s2])[4 * pc + 0]; v[1] = (*os[s2])[4 * pc + 1];
                v[2] = (*os[s2])[4 * pc + 2]; v[3] = (*os[s2])[4 * pc + 3];
                *(f32x4*)(pr + ((s2 * 4 + pc) * 64 + l) * 16) = v;
            }
        }
    }
    __syncthreads();

    // reduce over K-quarters: wave (ngx=w>>2, mix=(w>>1)&1, nix=w&1)
    {
        const int ngx = w >> 2;
        const int mix = (w >> 1) & 1;
        const int nix = w & 1;
        const int s2 = mix * 2 + nix;
        f32x16 sm;
#pragma unroll
        for (int q = 0; q < 16; ++q) sm[q] = 0.f;
#pragma unroll
        for (int kq2 = 0; kq2 < 4; ++kq2) {
            const char* pr = (const char*)Gs + (size_t)(kq2 * 2 + ngx) * 16384;
#pragma unroll
            for (int pc = 0; pc < 4; ++pc) {
                f32x4 v = *(const f32x4*)(pr + ((s2 * 4 + pc) * 64 + l) * 16);
                sm[4 * pc + 0] += v[0]; sm[4 * pc + 1] += v[1];
                sm[4 * pc + 2] += v[2]; sm[4 * pc + 3] += v[3];
            }
        }
        const int czl = ngx * 64 + nix * 32 + (l & 31);
        const int khx = l >> 5;
#pragma unroll
        for (int reg = 0; reg < 16; ++reg) {
            int pl = mix * 32 + (reg & 3) + 8 * (reg >> 2) + 4 * khx;
            int prr = pl >> 3, ptt = pl & 7;
            out[((size_t)(r0 + prr) * 256 + (t0 + ptt)) * 128 + czl] = sm[reg];
        }
    }
}

extern "C" void kernel_launch(void* const* d_in, const int* in_sizes, int n_in,
                              void* d_out, int out_size, void* d_ws, size_t ws_size,
                              hipStream_t stream) {
    const float* msa = (const float*)d_in[0];
    const float* left = (const float*)d_in[1];
    const float* right = (const float*)d_in[2];
    const float* W = (const float*)d_in[3];

    __bf16* aTf = (__bf16*)d_ws;                        // 2 MB
    __bf16* bTf = aTf + (size_t)R * 4096;               // 2 MB
    __bf16* WTf = bTf + (size_t)R * 4096;               // 256 KB
    __bf16* WLRT = WTf + (size_t)128 * 1024;            // 32 KB
    float* outp = (float*)d_out;

    k_prep<<<576, 256, 0, stream>>>(W, left, right, WTf, WLRT);
    k_proj<<<dim3(256, 4), 256, 0, stream>>>(msa, WLRT, aTf, bTf);
    k_main<<<dim3(32, 32), 512, 0, stream>>>(aTf, bTf, WTf, outp);
}